// Round 7
// baseline (917.735 us; speedup 1.0000x reference)
//
#include <hip/hip_runtime.h>
#include <math.h>

#define NN 16384
#define H 128
#define CODE 1024

typedef __attribute__((ext_vector_type(8))) short short8;
typedef __attribute__((ext_vector_type(4))) float f32x4;

// ---- ws layout (bytes) ----
#define OFF_WIN   0u            // [128][1024] bf16, stride 2048
#define OFF_WOUT  262144u       // [1024][128] bf16, stride 256
#define OFF_P     524288u       // 4 x [256][128] bf16, stride 256
#define OFF_N1    786432u       // 4 x [128][256] bf16, stride 512
#define OFF_N2    1048576u      // 4 x [128][128] bf16, stride 256
#define OFF_W2    1179648u      // 4 x [128][128] bf16 eW2^T, stride 256
#define OFF_H     1318912u                   // h   fp32  8388608
#define OFF_HN    (OFF_H + 8388608u)         // hn  fp32  8388608
#define OFF_PBUF  (OFF_HN + 8388608u)        // P   fp32  16777216
#define OFF_AGGB  (OFF_PBUF + 16777216u)     // agg bf16  4194304

__device__ __forceinline__ float silu(float x) { return x / (1.0f + __expf(-x)); }

__device__ __forceinline__ unsigned short f2bf(float f) {
    unsigned int u = __float_as_uint(f);
    u = (u + 0x7FFFu + ((u >> 16) & 1u)) >> 16;
    return (unsigned short)u;
}

__device__ __forceinline__ short8 cvtfrag(const float* p) {
    float4 a = *(const float4*)p;
    float4 b = *(const float4*)(p + 4);
    short8 r;
    r[0] = (short)f2bf(a.x); r[1] = (short)f2bf(a.y); r[2] = (short)f2bf(a.z); r[3] = (short)f2bf(a.w);
    r[4] = (short)f2bf(b.x); r[5] = (short)f2bf(b.y); r[6] = (short)f2bf(b.z); r[7] = (short)f2bf(b.w);
    return r;
}

// 26-stencil offsets (dx,dy,dz) of the radius graph
__device__ const int ODX[26] = {-1,-1,-1,-1,-1,-1,-1,-1,-1, 0,0,0,0,0,0,0,0, 1,1,1,1,1,1,1,1,1};
__device__ const int ODY[26] = {-1,-1,-1, 0, 0, 0, 1, 1, 1,-1,-1,-1,0,0,1,1,1,-1,-1,-1,0,0,0,1,1,1};
__device__ const int ODZ[26] = {-1, 0, 1,-1, 0, 1,-1, 0, 1,-1, 0, 1,-1,1,-1,0,1,-1, 0, 1,-1,0,1,-1,0,1};

// transposed bf16 weight images for all GEMMs
__global__ void k_prep(const float* __restrict__ W_in, const float* __restrict__ W_out,
                       const float* __restrict__ eW1, const float* __restrict__ nW1,
                       const float* __restrict__ nW2, const float* __restrict__ eW2,
                       char* __restrict__ base) {
    int t = blockIdx.x * 256 + threadIdx.x;
    if (t < 131072) {
        int n = t >> 10, k = t & 1023;
        *(unsigned short*)(base + OFF_WIN + n * 2048 + k * 2) = f2bf(W_in[k * 128 + n]);
        return;
    }
    t -= 131072;
    if (t < 131072) {
        int n = t >> 7, k = t & 127;
        *(unsigned short*)(base + OFF_WOUT + n * 256 + k * 2) = f2bf(W_out[k * 1024 + n]);
        return;
    }
    t -= 131072;
    if (t < 131072) {
        int l = t >> 15, r = t & 32767;
        int jj = r >> 7, k = r & 127;
        const float* W = eW1 + (size_t)l * 257 * 128;
        float v = (jj < 128) ? W[k * 128 + jj] : W[(128 + k) * 128 + (jj - 128)];
        *(unsigned short*)(base + OFF_P + (size_t)l * 65536 + jj * 256 + k * 2) = f2bf(v);
        return;
    }
    t -= 131072;
    if (t < 131072) {
        int l = t >> 15, r = t & 32767;
        int n = r >> 8, k = r & 255;
        *(unsigned short*)(base + OFF_N1 + (size_t)l * 65536 + n * 512 + k * 2) =
            f2bf(nW1[(size_t)l * 256 * 128 + k * 128 + n]);
        return;
    }
    t -= 131072;
    if (t < 65536) {
        int l = t >> 14, r = t & 16383;
        int n = r >> 7, k = r & 127;
        *(unsigned short*)(base + OFF_N2 + (size_t)l * 32768 + n * 256 + k * 2) =
            f2bf(nW2[(size_t)l * 128 * 128 + k * 128 + n]);
        return;
    }
    t -= 65536;
    if (t < 65536) {
        int l = t >> 14, r = t & 16383;
        int n = r >> 7, k = r & 127;
        *(unsigned short*)(base + OFF_W2 + (size_t)l * 32768 + n * 256 + k * 2) =
            f2bf(eW2[(size_t)l * 128 * 128 + k * 128 + n]);
    }
}

// ---------------- h = y @ W_in + b_in (MFMA) ----------------
__global__ __launch_bounds__(256) void k_in_mfma(const float* __restrict__ y,
                                                 const char* __restrict__ imgWin,
                                                 const float* __restrict__ bi,
                                                 float* __restrict__ h) {
    int tid = threadIdx.x, w = tid >> 6, lane = tid & 63;
    int l15 = lane & 15, kg = lane >> 4;
    int m0 = blockIdx.x * 64 + w * 16;
    const float* yr = y + (size_t)(m0 + l15) * CODE;
    f32x4 acc[8];
#pragma unroll
    for (int nt = 0; nt < 8; nt++) { f32x4 z = {0.f,0.f,0.f,0.f}; acc[nt] = z; }
#pragma unroll 4
    for (int ks = 0; ks < 32; ks++) {
        short8 a = cvtfrag(yr + ks * 32 + kg * 8);
        const char* bp = imgWin + ks * 64 + kg * 16;
#pragma unroll
        for (int nt = 0; nt < 8; nt++) {
            short8 b = *(const short8*)(bp + (nt * 16 + l15) * 2048);
            acc[nt] = __builtin_amdgcn_mfma_f32_16x16x32_bf16(a, b, acc[nt], 0, 0, 0);
        }
    }
#pragma unroll
    for (int nt = 0; nt < 8; nt++) {
        int cc = nt * 16 + l15;
        float bb = bi[cc];
#pragma unroll
        for (int r = 0; r < 4; r++)
            h[(size_t)(m0 + kg * 4 + r) * H + cc] = acc[nt][r] + bb;
    }
}

// ---------------- LayerNorm ----------------
__global__ void k_ln(const float* __restrict__ h, const float* __restrict__ g,
                     const float* __restrict__ b, float* __restrict__ hn) {
    int wave = threadIdx.x >> 6, lane = threadIdx.x & 63;
    int n = blockIdx.x * 4 + wave;
    const float* hr = h + (size_t)n * H;
    float x0 = hr[lane], x1 = hr[lane + 64];
    float s = x0 + x1;
#pragma unroll
    for (int off = 32; off; off >>= 1) s += __shfl_xor(s, off);
    float mu = s * (1.0f / 128.0f);
    float d0 = x0 - mu, d1 = x1 - mu;
    float v = d0 * d0 + d1 * d1;
#pragma unroll
    for (int off = 32; off; off >>= 1) v += __shfl_xor(v, off);
    float rs = rsqrtf(v * (1.0f / 128.0f) + 1e-5f);
    float* o = hn + (size_t)n * H;
    o[lane]      = d0 * rs * g[lane]      + b[lane];
    o[lane + 64] = d1 * rs * g[lane + 64] + b[lane + 64];
}

// ---------------- P = hn @ [W1a|W1b] (+b1 on upper half) (MFMA) ----------------
__global__ __launch_bounds__(256) void k_P_mfma(const float* __restrict__ hn,
                                                const char* __restrict__ imgP,
                                                const float* __restrict__ b1,
                                                float* __restrict__ P) {
    int bid = blockIdx.x;
    int rowblk = bid >> 1, nc = bid & 1;
    int tid = threadIdx.x, w = tid >> 6, lane = tid & 63;
    int l15 = lane & 15, kg = lane >> 4;
    int m0 = rowblk * 64 + w * 16;
    const float* hr = hn + (size_t)(m0 + l15) * H;
    short8 a[4];
#pragma unroll
    for (int ks = 0; ks < 4; ks++) a[ks] = cvtfrag(hr + ks * 32 + kg * 8);
    f32x4 acc[8];
#pragma unroll
    for (int nt = 0; nt < 8; nt++) { f32x4 z = {0.f,0.f,0.f,0.f}; acc[nt] = z; }
#pragma unroll
    for (int ks = 0; ks < 4; ks++) {
        const char* bp = imgP + (size_t)(nc * 128) * 256 + ks * 64 + kg * 16;
#pragma unroll
        for (int nt = 0; nt < 8; nt++) {
            short8 b = *(const short8*)(bp + (nt * 16 + l15) * 256);
            acc[nt] = __builtin_amdgcn_mfma_f32_16x16x32_bf16(a[ks], b, acc[nt], 0, 0, 0);
        }
    }
#pragma unroll
    for (int nt = 0; nt < 8; nt++) {
        int jj = nc * 128 + nt * 16 + l15;
        float add = nc ? b1[nt * 16 + l15] : 0.0f;
#pragma unroll
        for (int r = 0; r < 4; r++)
            P[(size_t)(m0 + kg * 4 + r) * 256 + jj] = acc[nt][r] + add;
    }
}

// ---------------- fused edge phase over the 26-stencil ----------------
// Block = 16 consecutive nodes (x,sample fixed). 4 waves split the 26 offsets.
// Per offset: A[r][k] = silu(P1[n_r+o][k] + P2[n_r][128+k] + d_o*w256[k]) built in
// registers in MFMA layout, GEMM vs eW2^T (L2), silu+mask, accumulate agg in C-layout.
__global__ __launch_bounds__(256) void k_edge_sten(
        const float* __restrict__ P, const char* __restrict__ imgW2,
        const float* __restrict__ w256f, const float* __restrict__ b2,
        char* __restrict__ aggb) {
    __shared__ float red[4][16][128];
    int tid = threadIdx.x, w = tid >> 6, lane = tid & 63;
    int l15 = lane & 15, kg = lane >> 4;
    int n0 = blockIdx.x * 16;
    int x = (n0 >> 6) & 7, y0 = (n0 >> 3) & 7;
    int n = n0 + l15;
    int ya = y0 + (l15 >> 3), za = l15 & 7;          // A-row coords
    int ye = y0 + (kg >> 1), ze = (kg & 1) * 4;      // C-row coords (rows ze..ze+3)

    // per-lane P2 slice: k = ks*32 + kg*8 + (0..7)  [R5 bug: was indexed ignoring kg]
    const float* p2r = P + (size_t)n * 256 + 128;
    float4 p2a[4], p2b[4];
#pragma unroll
    for (int ks = 0; ks < 4; ks++) {
        p2a[ks] = *(const float4*)(p2r + ks * 32 + kg * 8);
        p2b[ks] = *(const float4*)(p2r + ks * 32 + kg * 8 + 4);
    }
    float b2v[8];
#pragma unroll
    for (int nt = 0; nt < 8; nt++) b2v[nt] = b2[nt * 16 + l15];

    float accag[8][4];
#pragma unroll
    for (int nt = 0; nt < 8; nt++)
#pragma unroll
        for (int r = 0; r < 4; r++) accag[nt][r] = 0.0f;

    int ostart = (w * 26) >> 2, oend = ((w + 1) * 26) >> 2;
    for (int o = ostart; o < oend; ++o) {
        int dx = ODX[o], dy = ODY[o], dz = ODZ[o];
        int ux = x + dx;
        if ((unsigned)ux >= 8u) continue;            // whole offset invalid for block
        float d = sqrtf((float)(4 * (dx * dx + dy * dy + dz * dz)));
        bool va = ((unsigned)(ya + dy) < 8u) & ((unsigned)(za + dz) < 8u);
        int nb = va ? (n + dx * 64 + dy * 8 + dz) : n;
        const float* p1r = P + (size_t)nb * 256;

        f32x4 c[8];
#pragma unroll
        for (int nt = 0; nt < 8; nt++) { f32x4 z4 = {0.f,0.f,0.f,0.f}; c[nt] = z4; }
#pragma unroll
        for (int ks = 0; ks < 4; ks++) {
            float4 u0 = *(const float4*)(p1r + ks * 32 + kg * 8);
            float4 u1 = *(const float4*)(p1r + ks * 32 + kg * 8 + 4);
            float4 w0 = *(const float4*)(w256f + ks * 32 + kg * 8);
            float4 w1 = *(const float4*)(w256f + ks * 32 + kg * 8 + 4);
            float4 pa = p2a[ks], pb = p2b[ks];
            short8 a;
            a[0] = (short)f2bf(silu(u0.x + pa.x + d * w0.x));
            a[1] = (short)f2bf(silu(u0.y + pa.y + d * w0.y));
            a[2] = (short)f2bf(silu(u0.z + pa.z + d * w0.z));
            a[3] = (short)f2bf(silu(u0.w + pa.w + d * w0.w));
            a[4] = (short)f2bf(silu(u1.x + pb.x + d * w1.x));
            a[5] = (short)f2bf(silu(u1.y + pb.y + d * w1.y));
            a[6] = (short)f2bf(silu(u1.z + pb.z + d * w1.z));
            a[7] = (short)f2bf(silu(u1.w + pb.w + d * w1.w));
            const char* bp = imgW2 + ks * 64 + kg * 16;
#pragma unroll
            for (int nt = 0; nt < 8; nt++) {
                short8 b = *(const short8*)(bp + (nt * 16 + l15) * 256);
                c[nt] = __builtin_amdgcn_mfma_f32_16x16x32_bf16(a, b, c[nt], 0, 0, 0);
            }
        }
#pragma unroll
        for (int r = 0; r < 4; r++) {
            bool vr = ((unsigned)(ye + dy) < 8u) & ((unsigned)(ze + r + dz) < 8u);
#pragma unroll
            for (int nt = 0; nt < 8; nt++) {
                float v = silu(c[nt][r] + b2v[nt]);
                accag[nt][r] += vr ? v : 0.0f;
            }
        }
    }

#pragma unroll
    for (int nt = 0; nt < 8; nt++)
#pragma unroll
        for (int r = 0; r < 4; r++)
            red[w][kg * 4 + r][nt * 16 + l15] = accag[nt][r];
    __syncthreads();

    for (int i = tid; i < 2048; i += 256) {
        int row = i >> 7, colc = i & 127;
        float s = red[0][row][colc] + red[1][row][colc]
                + red[2][row][colc] + red[3][row][colc];
        int node = n0 + row;
        int xx = (node >> 6) & 7, yy = (node >> 3) & 7, zz = node & 7;
        int degc = (1 + (xx > 0) + (xx < 7)) * (1 + (yy > 0) + (yy < 7))
                 * (1 + (zz > 0) + (zz < 7)) - 1;
        float dinv = 1.0f / (float)degc;
        *(unsigned short*)(aggb + (size_t)node * 256 + colc * 2) = f2bf(s * dinv);
    }
}

// ---------------- fused node MLP + residual (MFMA x2) ----------------
__global__ __launch_bounds__(256) void k_node_mfma(
        const float* __restrict__ hn, const char* __restrict__ aggb,
        const char* __restrict__ imgN1, const float* __restrict__ nb1,
        const char* __restrict__ imgN2, const float* __restrict__ nb2,
        float* __restrict__ h) {
    __shared__ __align__(16) char sM[4][16 * 272];
    int tid = threadIdx.x, w = tid >> 6, lane = tid & 63;
    int l15 = lane & 15, kg = lane >> 4;
    int m0 = blockIdx.x * 64 + w * 16;
    const float* hr = hn + (size_t)(m0 + l15) * H;
    const char*  ar = aggb + (size_t)(m0 + l15) * 256;

    f32x4 acc[8];
#pragma unroll
    for (int nt = 0; nt < 8; nt++) { f32x4 z = {0.f,0.f,0.f,0.f}; acc[nt] = z; }
#pragma unroll
    for (int ks = 0; ks < 8; ks++) {
        short8 a;
        if (ks < 4) a = cvtfrag(hr + ks * 32 + kg * 8);
        else        a = *(const short8*)(ar + (ks - 4) * 64 + kg * 16);
        const char* bp = imgN1 + ks * 64 + kg * 16;
#pragma unroll
        for (int nt = 0; nt < 8; nt++) {
            short8 b = *(const short8*)(bp + (nt * 16 + l15) * 512);
            acc[nt] = __builtin_amdgcn_mfma_f32_16x16x32_bf16(a, b, acc[nt], 0, 0, 0);
        }
    }
#pragma unroll
    for (int nt = 0; nt < 8; nt++) {
        int cc = nt * 16 + l15;
        float bb = nb1[cc];
#pragma unroll
        for (int r = 0; r < 4; r++) {
            float v = silu(acc[nt][r] + bb);
            *(unsigned short*)(&sM[w][(kg * 4 + r) * 272 + cc * 2]) = f2bf(v);
        }
    }
    f32x4 acc2[8];
#pragma unroll
    for (int nt = 0; nt < 8; nt++) { f32x4 z = {0.f,0.f,0.f,0.f}; acc2[nt] = z; }
#pragma unroll
    for (int ks = 0; ks < 4; ks++) {
        short8 a = *(const short8*)(&sM[w][l15 * 272 + ks * 64 + kg * 16]);
        const char* bp = imgN2 + ks * 64 + kg * 16;
#pragma unroll
        for (int nt = 0; nt < 8; nt++) {
            short8 b = *(const short8*)(bp + (nt * 16 + l15) * 256);
            acc2[nt] = __builtin_amdgcn_mfma_f32_16x16x32_bf16(a, b, acc2[nt], 0, 0, 0);
        }
    }
#pragma unroll
    for (int nt = 0; nt < 8; nt++) {
        int cc = nt * 16 + l15;
        float bb = nb2[cc];
#pragma unroll
        for (int r = 0; r < 4; r++) {
            size_t idx = (size_t)(m0 + kg * 4 + r) * H + cc;
            h[idx] = hn[idx] + acc2[nt][r] + bb;
        }
    }
}

// ---------------- out = h @ W_out + b_out (MFMA, N-parallel) ----------------
__global__ __launch_bounds__(256) void k_out_mfma(const float* __restrict__ h,
                                                  const char* __restrict__ imgWout,
                                                  const float* __restrict__ bo,
                                                  float* __restrict__ out) {
    int bid = blockIdx.x;
    int rowblk = bid >> 3, nc = bid & 7;
    int tid = threadIdx.x, w = tid >> 6, lane = tid & 63;
    int l15 = lane & 15, kg = lane >> 4;
    int m0 = rowblk * 64 + w * 16;
    const float* hr = h + (size_t)(m0 + l15) * H;
    short8 a[4];
#pragma unroll
    for (int ks = 0; ks < 4; ks++) a[ks] = cvtfrag(hr + ks * 32 + kg * 8);
    f32x4 acc[8];
#pragma unroll
    for (int nt = 0; nt < 8; nt++) { f32x4 z = {0.f,0.f,0.f,0.f}; acc[nt] = z; }
#pragma unroll
    for (int ks = 0; ks < 4; ks++) {
        const char* bp = imgWout + (size_t)(nc * 128) * 256 + ks * 64 + kg * 16;
#pragma unroll
        for (int nt = 0; nt < 8; nt++) {
            short8 b = *(const short8*)(bp + (nt * 16 + l15) * 256);
            acc[nt] = __builtin_amdgcn_mfma_f32_16x16x32_bf16(a[ks], b, acc[nt], 0, 0, 0);
        }
    }
#pragma unroll
    for (int nt = 0; nt < 8; nt++) {
        int cc = nc * 128 + nt * 16 + l15;
        float bb = bo[cc];
#pragma unroll
        for (int r = 0; r < 4; r++)
            out[(size_t)(m0 + kg * 4 + r) * 1024 + cc] = acc[nt][r] + bb;
    }
}

extern "C" void kernel_launch(void* const* d_in, const int* in_sizes, int n_in,
                              void* d_out, int out_size, void* d_ws, size_t ws_size,
                              hipStream_t stream) {
    const float* y     = (const float*)d_in[0];
    const float* W_in  = (const float*)d_in[3];
    const float* b_in  = (const float*)d_in[4];
    const float* ln_g  = (const float*)d_in[5];
    const float* ln_b  = (const float*)d_in[6];
    const float* eW1   = (const float*)d_in[7];
    const float* eb1   = (const float*)d_in[8];
    const float* eW2   = (const float*)d_in[9];
    const float* eb2   = (const float*)d_in[10];
    const float* nW1   = (const float*)d_in[11];
    const float* nb1   = (const float*)d_in[12];
    const float* nW2   = (const float*)d_in[13];
    const float* nb2   = (const float*)d_in[14];
    const float* W_out = (const float*)d_in[15];
    const float* b_out = (const float*)d_in[16];

    char* wsb = (char*)d_ws;
    float* h    = (float*)(wsb + OFF_H);
    float* hn   = (float*)(wsb + OFF_HN);
    float* P    = (float*)(wsb + OFF_PBUF);
    char*  aggb = wsb + OFF_AGGB;

    k_prep<<<655360 / 256, 256, 0, stream>>>(W_in, W_out, eW1, nW1, nW2, eW2, wsb);
    k_in_mfma<<<NN / 64, 256, 0, stream>>>(y, wsb + OFF_WIN, b_in, h);
    for (int l = 0; l < 4; ++l) {
        k_ln<<<NN / 4, 256, 0, stream>>>(h, ln_g + l * H, ln_b + l * H, hn);
        k_P_mfma<<<NN / 64 * 2, 256, 0, stream>>>(hn, wsb + OFF_P + (size_t)l * 65536,
                                                  eb1 + l * H, P);
        k_edge_sten<<<NN / 16, 256, 0, stream>>>(P, wsb + OFF_W2 + (size_t)l * 32768,
                                                 eW1 + (size_t)l * 257 * H + 256 * H,
                                                 eb2 + l * H, aggb);
        k_node_mfma<<<NN / 64, 256, 0, stream>>>(hn, aggb,
                                                 wsb + OFF_N1 + (size_t)l * 65536, nb1 + l * H,
                                                 wsb + OFF_N2 + (size_t)l * 32768, nb2 + l * H, h);
    }
    k_out_mfma<<<NN / 64 * 8, 256, 0, stream>>>(h, wsb + OFF_WOUT, b_out, (float*)d_out);
}

// Round 8
// 757.721 us; speedup vs baseline: 1.2112x; 1.2112x over previous
//
#include <hip/hip_runtime.h>
#include <math.h>

#define NN 16384
#define H 128
#define CODE 1024

typedef __attribute__((ext_vector_type(8))) short short8;
typedef __attribute__((ext_vector_type(4))) float f32x4;

// ---- ws layout (bytes) ----
#define OFF_WIN   0u            // [128][1024] bf16, stride 2048
#define OFF_WOUT  262144u       // [1024][128] bf16, stride 256
#define OFF_P     524288u       // 4 x [256][128] bf16 (eW1 split), stride 256
#define OFF_N1    786432u       // 4 x [128][256] bf16, stride 512
#define OFF_N2    1048576u      // 4 x [128][128] bf16, stride 256
#define OFF_W2    1179648u      // 4 x [128][128] bf16 eW2^T, stride 256
#define OFF_H     1318912u                   // h   fp32  8388608
#define OFF_HN    (OFF_H + 8388608u)         // hn  fp32  8388608
#define OFF_PBUF  (OFF_HN + 8388608u)        // P  BF16 [NN][256]  8388608
#define OFF_AGGB  (OFF_PBUF + 16777216u)     // agg bf16  4194304

__device__ __forceinline__ float silu(float x) { return x / (1.0f + __expf(-x)); }

__device__ __forceinline__ unsigned short f2bf(float f) {
    unsigned int u = __float_as_uint(f);
    u = (u + 0x7FFFu + ((u >> 16) & 1u)) >> 16;
    return (unsigned short)u;
}

__device__ __forceinline__ float bf2f(short s) {
    return __uint_as_float(((unsigned)(unsigned short)s) << 16);
}

__device__ __forceinline__ short8 cvtfrag(const float* p) {
    float4 a = *(const float4*)p;
    float4 b = *(const float4*)(p + 4);
    short8 r;
    r[0] = (short)f2bf(a.x); r[1] = (short)f2bf(a.y); r[2] = (short)f2bf(a.z); r[3] = (short)f2bf(a.w);
    r[4] = (short)f2bf(b.x); r[5] = (short)f2bf(b.y); r[6] = (short)f2bf(b.z); r[7] = (short)f2bf(b.w);
    return r;
}

// 26-stencil offsets (dx,dy,dz) of the radius graph
__device__ const int ODX[26] = {-1,-1,-1,-1,-1,-1,-1,-1,-1, 0,0,0,0,0,0,0,0, 1,1,1,1,1,1,1,1,1};
__device__ const int ODY[26] = {-1,-1,-1, 0, 0, 0, 1, 1, 1,-1,-1,-1,0,0,1,1,1,-1,-1,-1,0,0,0,1,1,1};
__device__ const int ODZ[26] = {-1, 0, 1,-1, 0, 1,-1, 0, 1,-1, 0, 1,-1,1,-1,0,1,-1, 0, 1,-1,0,1,-1,0,1};

// transposed bf16 weight images for all GEMMs
__global__ void k_prep(const float* __restrict__ W_in, const float* __restrict__ W_out,
                       const float* __restrict__ eW1, const float* __restrict__ nW1,
                       const float* __restrict__ nW2, const float* __restrict__ eW2,
                       char* __restrict__ base) {
    int t = blockIdx.x * 256 + threadIdx.x;
    if (t < 131072) {
        int n = t >> 10, k = t & 1023;
        *(unsigned short*)(base + OFF_WIN + n * 2048 + k * 2) = f2bf(W_in[k * 128 + n]);
        return;
    }
    t -= 131072;
    if (t < 131072) {
        int n = t >> 7, k = t & 127;
        *(unsigned short*)(base + OFF_WOUT + n * 256 + k * 2) = f2bf(W_out[k * 1024 + n]);
        return;
    }
    t -= 131072;
    if (t < 131072) {
        int l = t >> 15, r = t & 32767;
        int jj = r >> 7, k = r & 127;
        const float* W = eW1 + (size_t)l * 257 * 128;
        float v = (jj < 128) ? W[k * 128 + jj] : W[(128 + k) * 128 + (jj - 128)];
        *(unsigned short*)(base + OFF_P + (size_t)l * 65536 + jj * 256 + k * 2) = f2bf(v);
        return;
    }
    t -= 131072;
    if (t < 131072) {
        int l = t >> 15, r = t & 32767;
        int n = r >> 8, k = r & 255;
        *(unsigned short*)(base + OFF_N1 + (size_t)l * 65536 + n * 512 + k * 2) =
            f2bf(nW1[(size_t)l * 256 * 128 + k * 128 + n]);
        return;
    }
    t -= 131072;
    if (t < 65536) {
        int l = t >> 14, r = t & 16383;
        int n = r >> 7, k = r & 127;
        *(unsigned short*)(base + OFF_N2 + (size_t)l * 32768 + n * 256 + k * 2) =
            f2bf(nW2[(size_t)l * 128 * 128 + k * 128 + n]);
        return;
    }
    t -= 65536;
    if (t < 65536) {
        int l = t >> 14, r = t & 16383;
        int n = r >> 7, k = r & 127;
        *(unsigned short*)(base + OFF_W2 + (size_t)l * 32768 + n * 256 + k * 2) =
            f2bf(eW2[(size_t)l * 128 * 128 + k * 128 + n]);
    }
}

// ---------------- h = y @ W_in + b_in (MFMA) ----------------
__global__ __launch_bounds__(256) void k_in_mfma(const float* __restrict__ y,
                                                 const char* __restrict__ imgWin,
                                                 const float* __restrict__ bi,
                                                 float* __restrict__ h) {
    int tid = threadIdx.x, w = tid >> 6, lane = tid & 63;
    int l15 = lane & 15, kg = lane >> 4;
    int m0 = blockIdx.x * 64 + w * 16;
    const float* yr = y + (size_t)(m0 + l15) * CODE;
    f32x4 acc[8];
#pragma unroll
    for (int nt = 0; nt < 8; nt++) { f32x4 z = {0.f,0.f,0.f,0.f}; acc[nt] = z; }
#pragma unroll 4
    for (int ks = 0; ks < 32; ks++) {
        short8 a = cvtfrag(yr + ks * 32 + kg * 8);
        const char* bp = imgWin + ks * 64 + kg * 16;
#pragma unroll
        for (int nt = 0; nt < 8; nt++) {
            short8 b = *(const short8*)(bp + (nt * 16 + l15) * 2048);
            acc[nt] = __builtin_amdgcn_mfma_f32_16x16x32_bf16(a, b, acc[nt], 0, 0, 0);
        }
    }
#pragma unroll
    for (int nt = 0; nt < 8; nt++) {
        int cc = nt * 16 + l15;
        float bb = bi[cc];
#pragma unroll
        for (int r = 0; r < 4; r++)
            h[(size_t)(m0 + kg * 4 + r) * H + cc] = acc[nt][r] + bb;
    }
}

// ---------------- LayerNorm ----------------
__global__ void k_ln(const float* __restrict__ h, const float* __restrict__ g,
                     const float* __restrict__ b, float* __restrict__ hn) {
    int wave = threadIdx.x >> 6, lane = threadIdx.x & 63;
    int n = blockIdx.x * 4 + wave;
    const float* hr = h + (size_t)n * H;
    float x0 = hr[lane], x1 = hr[lane + 64];
    float s = x0 + x1;
#pragma unroll
    for (int off = 32; off; off >>= 1) s += __shfl_xor(s, off);
    float mu = s * (1.0f / 128.0f);
    float d0 = x0 - mu, d1 = x1 - mu;
    float v = d0 * d0 + d1 * d1;
#pragma unroll
    for (int off = 32; off; off >>= 1) v += __shfl_xor(v, off);
    float rs = rsqrtf(v * (1.0f / 128.0f) + 1e-5f);
    float* o = hn + (size_t)n * H;
    o[lane]      = d0 * rs * g[lane]      + b[lane];
    o[lane + 64] = d1 * rs * g[lane + 64] + b[lane + 64];
}

// ---------------- P = hn @ [W1a|W1b] (+b1 on upper half), OUTPUT BF16 ----------------
__global__ __launch_bounds__(256) void k_P_mfma(const float* __restrict__ hn,
                                                const char* __restrict__ imgP,
                                                const float* __restrict__ b1,
                                                unsigned short* __restrict__ Pb) {
    int bid = blockIdx.x;
    int rowblk = bid >> 1, nc = bid & 1;
    int tid = threadIdx.x, w = tid >> 6, lane = tid & 63;
    int l15 = lane & 15, kg = lane >> 4;
    int m0 = rowblk * 64 + w * 16;
    const float* hr = hn + (size_t)(m0 + l15) * H;
    short8 a[4];
#pragma unroll
    for (int ks = 0; ks < 4; ks++) a[ks] = cvtfrag(hr + ks * 32 + kg * 8);
    f32x4 acc[8];
#pragma unroll
    for (int nt = 0; nt < 8; nt++) { f32x4 z = {0.f,0.f,0.f,0.f}; acc[nt] = z; }
#pragma unroll
    for (int ks = 0; ks < 4; ks++) {
        const char* bp = imgP + (size_t)(nc * 128) * 256 + ks * 64 + kg * 16;
#pragma unroll
        for (int nt = 0; nt < 8; nt++) {
            short8 b = *(const short8*)(bp + (nt * 16 + l15) * 256);
            acc[nt] = __builtin_amdgcn_mfma_f32_16x16x32_bf16(a[ks], b, acc[nt], 0, 0, 0);
        }
    }
#pragma unroll
    for (int nt = 0; nt < 8; nt++) {
        int jj = nc * 128 + nt * 16 + l15;
        float add = nc ? b1[nt * 16 + l15] : 0.0f;
#pragma unroll
        for (int r = 0; r < 4; r++)
            Pb[(size_t)(m0 + kg * 4 + r) * 256 + jj] = f2bf(acc[nt][r] + add);
    }
}

// ---------------- fused edge phase: LDS-staged stencil ----------------
// Block = 64 nodes (full yz-plane at fixed sample,x). Stage 3 x-planes of P1
// (bf16, XOR-swizzled) in LDS. Each wave owns 16 nodes x all 26 offsets; agg
// accumulated in C-layout registers; no cross-wave reduce, 1 barrier total.
__global__ __launch_bounds__(256) void k_edge_sten(
        const unsigned short* __restrict__ Pb, const char* __restrict__ imgW2,
        const float* __restrict__ w256f, const float* __restrict__ b2,
        char* __restrict__ aggb) {
    __shared__ __align__(16) char sP1[3 * 16384];   // 48 KB
    int tid = threadIdx.x, w = tid >> 6, lane = tid & 63;
    int l15 = lane & 15, kg = lane >> 4;
    int n0 = blockIdx.x * 64;
    int x = (n0 >> 6) & 7;

    // stage 3 x-planes of P1 bf16 -> swizzled LDS (unit ^ (row&15))
#pragma unroll
    for (int i = 0; i < 12; i++) {
        int u = tid + i * 256;
        int p = u >> 10, rem = u & 1023;
        int row = rem >> 4, unit = rem & 15;
        int xp = x + p - 1;
        if ((unsigned)xp < 8u) {
            const char* src = (const char*)Pb + (size_t)(n0 + (p - 1) * 64 + row) * 512 + unit * 16;
            uint4 v = *(const uint4*)src;
            *(uint4*)(sP1 + p * 16384 + row * 256 + ((unit ^ (row & 15)) << 4)) = v;
        }
    }
    __syncthreads();

    int rowbase = w * 16 + l15;                    // A-row index in plane (0..63)
    int ya = rowbase >> 3, za = rowbase & 7;

    // own-node P2 slice (k = ks*32 + kg*8 + i) -> f32 regs
    float p2f[32], wf[32];
    const char* p2p = (const char*)Pb + (size_t)(n0 + rowbase) * 512 + 256;
#pragma unroll
    for (int ks = 0; ks < 4; ks++) {
        short8 s = *(const short8*)(p2p + ks * 64 + kg * 16);
#pragma unroll
        for (int i = 0; i < 8; i++) p2f[ks * 8 + i] = bf2f(s[i]);
        float4 a4 = *(const float4*)(w256f + ks * 32 + kg * 8);
        float4 b4 = *(const float4*)(w256f + ks * 32 + kg * 8 + 4);
        wf[ks*8+0]=a4.x; wf[ks*8+1]=a4.y; wf[ks*8+2]=a4.z; wf[ks*8+3]=a4.w;
        wf[ks*8+4]=b4.x; wf[ks*8+5]=b4.y; wf[ks*8+6]=b4.z; wf[ks*8+7]=b4.w;
    }
    float b2v[8];
#pragma unroll
    for (int nt = 0; nt < 8; nt++) b2v[nt] = b2[nt * 16 + l15];

    float accag[8][4];
#pragma unroll
    for (int nt = 0; nt < 8; nt++)
#pragma unroll
        for (int r = 0; r < 4; r++) accag[nt][r] = 0.0f;

    int ye = w * 2 + (kg >> 1), ze = (kg & 1) * 4;  // C-row coords

#pragma unroll 2
    for (int o = 0; o < 26; ++o) {
        int dx = ODX[o], dy = ODY[o], dz = ODZ[o];
        if ((unsigned)(x + dx) >= 8u) continue;      // uniform skip
        float d = sqrtf((float)(4 * (dx * dx + dy * dy + dz * dz)));
        bool va = ((unsigned)(ya + dy) < 8u) & ((unsigned)(za + dz) < 8u);
        int rowr = va ? (rowbase + dy * 8 + dz) : rowbase;
        const char* ap = sP1 + (dx + 1) * 16384 + rowr * 256;
        int rsw = rowr & 15;

        f32x4 c[8];
#pragma unroll
        for (int nt = 0; nt < 8; nt++) { f32x4 z4 = {0.f,0.f,0.f,0.f}; c[nt] = z4; }
#pragma unroll
        for (int ks = 0; ks < 4; ks++) {
            short8 s = *(const short8*)(ap + (((ks * 4 + kg) ^ rsw) << 4));
            short8 a;
#pragma unroll
            for (int i = 0; i < 8; i++) {
                float v = bf2f(s[i]) + p2f[ks * 8 + i] + d * wf[ks * 8 + i];
                a[i] = (short)f2bf(silu(v));
            }
            const char* bp = imgW2 + ks * 64 + kg * 16;
#pragma unroll
            for (int nt = 0; nt < 8; nt++) {
                short8 b = *(const short8*)(bp + (nt * 16 + l15) * 256);
                c[nt] = __builtin_amdgcn_mfma_f32_16x16x32_bf16(a, b, c[nt], 0, 0, 0);
            }
        }
#pragma unroll
        for (int r = 0; r < 4; r++) {
            bool vr = ((unsigned)(ye + dy) < 8u) & ((unsigned)(ze + r + dz) < 8u);
#pragma unroll
            for (int nt = 0; nt < 8; nt++) {
                float v = silu(c[nt][r] + b2v[nt]);
                accag[nt][r] += vr ? v : 0.0f;
            }
        }
    }

    // write agg (bf16) with arithmetic degree
#pragma unroll
    for (int r = 0; r < 4; r++) {
        int node = n0 + w * 16 + kg * 4 + r;
        int yy = (node >> 3) & 7, zz = node & 7;
        int degc = (1 + (x > 0) + (x < 7)) * (1 + (yy > 0) + (yy < 7))
                 * (1 + (zz > 0) + (zz < 7)) - 1;
        float dinv = 1.0f / (float)degc;
#pragma unroll
        for (int nt = 0; nt < 8; nt++)
            *(unsigned short*)(aggb + (size_t)node * 256 + (nt * 16 + l15) * 2) =
                f2bf(accag[nt][r] * dinv);
    }
}

// ---------------- fused node MLP + residual (MFMA x2) ----------------
__global__ __launch_bounds__(256) void k_node_mfma(
        const float* __restrict__ hn, const char* __restrict__ aggb,
        const char* __restrict__ imgN1, const float* __restrict__ nb1,
        const char* __restrict__ imgN2, const float* __restrict__ nb2,
        float* __restrict__ h) {
    __shared__ __align__(16) char sM[4][16 * 272];
    int tid = threadIdx.x, w = tid >> 6, lane = tid & 63;
    int l15 = lane & 15, kg = lane >> 4;
    int m0 = blockIdx.x * 64 + w * 16;
    const float* hr = hn + (size_t)(m0 + l15) * H;
    const char*  ar = aggb + (size_t)(m0 + l15) * 256;

    f32x4 acc[8];
#pragma unroll
    for (int nt = 0; nt < 8; nt++) { f32x4 z = {0.f,0.f,0.f,0.f}; acc[nt] = z; }
#pragma unroll
    for (int ks = 0; ks < 8; ks++) {
        short8 a;
        if (ks < 4) a = cvtfrag(hr + ks * 32 + kg * 8);
        else        a = *(const short8*)(ar + (ks - 4) * 64 + kg * 16);
        const char* bp = imgN1 + ks * 64 + kg * 16;
#pragma unroll
        for (int nt = 0; nt < 8; nt++) {
            short8 b = *(const short8*)(bp + (nt * 16 + l15) * 512);
            acc[nt] = __builtin_amdgcn_mfma_f32_16x16x32_bf16(a, b, acc[nt], 0, 0, 0);
        }
    }
#pragma unroll
    for (int nt = 0; nt < 8; nt++) {
        int cc = nt * 16 + l15;
        float bb = nb1[cc];
#pragma unroll
        for (int r = 0; r < 4; r++) {
            float v = silu(acc[nt][r] + bb);
            *(unsigned short*)(&sM[w][(kg * 4 + r) * 272 + cc * 2]) = f2bf(v);
        }
    }
    f32x4 acc2[8];
#pragma unroll
    for (int nt = 0; nt < 8; nt++) { f32x4 z = {0.f,0.f,0.f,0.f}; acc2[nt] = z; }
#pragma unroll
    for (int ks = 0; ks < 4; ks++) {
        short8 a = *(const short8*)(&sM[w][l15 * 272 + ks * 64 + kg * 16]);
        const char* bp = imgN2 + ks * 64 + kg * 16;
#pragma unroll
        for (int nt = 0; nt < 8; nt++) {
            short8 b = *(const short8*)(bp + (nt * 16 + l15) * 256);
            acc2[nt] = __builtin_amdgcn_mfma_f32_16x16x32_bf16(a, b, acc2[nt], 0, 0, 0);
        }
    }
#pragma unroll
    for (int nt = 0; nt < 8; nt++) {
        int cc = nt * 16 + l15;
        float bb = nb2[cc];
#pragma unroll
        for (int r = 0; r < 4; r++) {
            size_t idx = (size_t)(m0 + kg * 4 + r) * H + cc;
            h[idx] = hn[idx] + acc2[nt][r] + bb;
        }
    }
}

// ---------------- out = h @ W_out + b_out (MFMA, N-parallel) ----------------
__global__ __launch_bounds__(256) void k_out_mfma(const float* __restrict__ h,
                                                  const char* __restrict__ imgWout,
                                                  const float* __restrict__ bo,
                                                  float* __restrict__ out) {
    int bid = blockIdx.x;
    int rowblk = bid >> 3, nc = bid & 7;
    int tid = threadIdx.x, w = tid >> 6, lane = tid & 63;
    int l15 = lane & 15, kg = lane >> 4;
    int m0 = rowblk * 64 + w * 16;
    const float* hr = h + (size_t)(m0 + l15) * H;
    short8 a[4];
#pragma unroll
    for (int ks = 0; ks < 4; ks++) a[ks] = cvtfrag(hr + ks * 32 + kg * 8);
    f32x4 acc[8];
#pragma unroll
    for (int nt = 0; nt < 8; nt++) { f32x4 z = {0.f,0.f,0.f,0.f}; acc[nt] = z; }
#pragma unroll
    for (int ks = 0; ks < 4; ks++) {
        const char* bp = imgWout + (size_t)(nc * 128) * 256 + ks * 64 + kg * 16;
#pragma unroll
        for (int nt = 0; nt < 8; nt++) {
            short8 b = *(const short8*)(bp + (nt * 16 + l15) * 256);
            acc[nt] = __builtin_amdgcn_mfma_f32_16x16x32_bf16(a[ks], b, acc[nt], 0, 0, 0);
        }
    }
#pragma unroll
    for (int nt = 0; nt < 8; nt++) {
        int cc = nc * 128 + nt * 16 + l15;
        float bb = bo[cc];
#pragma unroll
        for (int r = 0; r < 4; r++)
            out[(size_t)(m0 + kg * 4 + r) * 1024 + cc] = acc[nt][r] + bb;
    }
}

extern "C" void kernel_launch(void* const* d_in, const int* in_sizes, int n_in,
                              void* d_out, int out_size, void* d_ws, size_t ws_size,
                              hipStream_t stream) {
    const float* y     = (const float*)d_in[0];
    const float* W_in  = (const float*)d_in[3];
    const float* b_in  = (const float*)d_in[4];
    const float* ln_g  = (const float*)d_in[5];
    const float* ln_b  = (const float*)d_in[6];
    const float* eW1   = (const float*)d_in[7];
    const float* eb1   = (const float*)d_in[8];
    const float* eW2   = (const float*)d_in[9];
    const float* eb2   = (const float*)d_in[10];
    const float* nW1   = (const float*)d_in[11];
    const float* nb1   = (const float*)d_in[12];
    const float* nW2   = (const float*)d_in[13];
    const float* nb2   = (const float*)d_in[14];
    const float* W_out = (const float*)d_in[15];
    const float* b_out = (const float*)d_in[16];

    char* wsb = (char*)d_ws;
    float* h    = (float*)(wsb + OFF_H);
    float* hn   = (float*)(wsb + OFF_HN);
    unsigned short* Pb = (unsigned short*)(wsb + OFF_PBUF);
    char*  aggb = wsb + OFF_AGGB;

    k_prep<<<655360 / 256, 256, 0, stream>>>(W_in, W_out, eW1, nW1, nW2, eW2, wsb);
    k_in_mfma<<<NN / 64, 256, 0, stream>>>(y, wsb + OFF_WIN, b_in, h);
    for (int l = 0; l < 4; ++l) {
        k_ln<<<NN / 4, 256, 0, stream>>>(h, ln_g + l * H, ln_b + l * H, hn);
        k_P_mfma<<<NN / 64 * 2, 256, 0, stream>>>(hn, wsb + OFF_P + (size_t)l * 65536,
                                                  eb1 + l * H, Pb);
        k_edge_sten<<<NN / 64, 256, 0, stream>>>(Pb, wsb + OFF_W2 + (size_t)l * 32768,
                                                 eW1 + (size_t)l * 257 * H + 256 * H,
                                                 eb2 + l * H, aggb);
        k_node_mfma<<<NN / 64, 256, 0, stream>>>(hn, aggb,
                                                 wsb + OFF_N1 + (size_t)l * 65536, nb1 + l * H,
                                                 wsb + OFF_N2 + (size_t)l * 32768, nb2 + l * H, h);
    }
    k_out_mfma<<<NN / 64 * 8, 256, 0, stream>>>(h, wsb + OFF_WOUT, b_out, (float*)d_out);
}

// Round 9
// 613.898 us; speedup vs baseline: 1.4949x; 1.2343x over previous
//
#include <hip/hip_runtime.h>
#include <math.h>

#define NN 16384
#define H 128
#define CODE 1024
#define RSTR 130   // red stride (f32 words) to dodge 4-way bank conflict

typedef __attribute__((ext_vector_type(8))) short short8;
typedef __attribute__((ext_vector_type(4))) float f32x4;

// ---- ws layout (bytes) ----
#define OFF_WIN   0u            // [128][1024] bf16, stride 2048
#define OFF_WOUT  262144u       // [1024][128] bf16, stride 256
#define OFF_P     524288u       // 4 x [256][128] bf16 (eW1 split), stride 256
#define OFF_N1    786432u       // 4 x [128][256] bf16, stride 512
#define OFF_N2    1048576u      // 4 x [128][128] bf16, stride 256
#define OFF_W2    1179648u      // 4 x [128][128] bf16 eW2^T, stride 256
#define OFF_H     1318912u                   // h   fp32  8388608
#define OFF_HN    (OFF_H + 8388608u)         // hn  fp32  8388608
#define OFF_PBUF  (OFF_HN + 8388608u)        // P  BF16 [NN][256]  8388608
#define OFF_AGGB  (OFF_PBUF + 16777216u)     // agg bf16  4194304

__device__ __forceinline__ float silu(float x) { return x / (1.0f + __expf(-x)); }

__device__ __forceinline__ unsigned short f2bf(float f) {
    unsigned int u = __float_as_uint(f);
    u = (u + 0x7FFFu + ((u >> 16) & 1u)) >> 16;
    return (unsigned short)u;
}

__device__ __forceinline__ float bf2f(short s) {
    return __uint_as_float(((unsigned)(unsigned short)s) << 16);
}

__device__ __forceinline__ short8 cvtfrag(const float* p) {
    float4 a = *(const float4*)p;
    float4 b = *(const float4*)(p + 4);
    short8 r;
    r[0] = (short)f2bf(a.x); r[1] = (short)f2bf(a.y); r[2] = (short)f2bf(a.z); r[3] = (short)f2bf(a.w);
    r[4] = (short)f2bf(b.x); r[5] = (short)f2bf(b.y); r[6] = (short)f2bf(b.z); r[7] = (short)f2bf(b.w);
    return r;
}

// 26-stencil offsets, GROUPED: [0,8)=corners, [8,20)=edges, [20,26)=faces.
// Wave-group 0 takes o in [0,13), group 1 takes [13,26).
__device__ const int SDX[26] = {-1,-1,-1,-1, 1, 1, 1, 1,  -1,-1,-1,-1, 0,  0, 0, 0, 1, 1, 1, 1,  -1, 1, 0, 0, 0, 0};
__device__ const int SDY[26] = {-1,-1, 1, 1,-1,-1, 1, 1,  -1, 0, 0, 1,-1, -1, 1, 1,-1, 0, 0, 1,   0, 0,-1, 1, 0, 0};
__device__ const int SDZ[26] = {-1, 1,-1, 1,-1, 1,-1, 1,   0,-1, 1, 0,-1,  1,-1, 1, 0,-1, 1, 0,   0, 0, 0, 0,-1, 1};

// transposed bf16 weight images for all GEMMs
__global__ void k_prep(const float* __restrict__ W_in, const float* __restrict__ W_out,
                       const float* __restrict__ eW1, const float* __restrict__ nW1,
                       const float* __restrict__ nW2, const float* __restrict__ eW2,
                       char* __restrict__ base) {
    int t = blockIdx.x * 256 + threadIdx.x;
    if (t < 131072) {
        int n = t >> 10, k = t & 1023;
        *(unsigned short*)(base + OFF_WIN + n * 2048 + k * 2) = f2bf(W_in[k * 128 + n]);
        return;
    }
    t -= 131072;
    if (t < 131072) {
        int n = t >> 7, k = t & 127;
        *(unsigned short*)(base + OFF_WOUT + n * 256 + k * 2) = f2bf(W_out[k * 1024 + n]);
        return;
    }
    t -= 131072;
    if (t < 131072) {
        int l = t >> 15, r = t & 32767;
        int jj = r >> 7, k = r & 127;
        const float* W = eW1 + (size_t)l * 257 * 128;
        float v = (jj < 128) ? W[k * 128 + jj] : W[(128 + k) * 128 + (jj - 128)];
        *(unsigned short*)(base + OFF_P + (size_t)l * 65536 + jj * 256 + k * 2) = f2bf(v);
        return;
    }
    t -= 131072;
    if (t < 131072) {
        int l = t >> 15, r = t & 32767;
        int n = r >> 8, k = r & 255;
        *(unsigned short*)(base + OFF_N1 + (size_t)l * 65536 + n * 512 + k * 2) =
            f2bf(nW1[(size_t)l * 256 * 128 + k * 128 + n]);
        return;
    }
    t -= 131072;
    if (t < 65536) {
        int l = t >> 14, r = t & 16383;
        int n = r >> 7, k = r & 127;
        *(unsigned short*)(base + OFF_N2 + (size_t)l * 32768 + n * 256 + k * 2) =
            f2bf(nW2[(size_t)l * 128 * 128 + k * 128 + n]);
        return;
    }
    t -= 65536;
    if (t < 65536) {
        int l = t >> 14, r = t & 16383;
        int n = r >> 7, k = r & 127;
        *(unsigned short*)(base + OFF_W2 + (size_t)l * 32768 + n * 256 + k * 2) =
            f2bf(eW2[(size_t)l * 128 * 128 + k * 128 + n]);
    }
}

// ---------------- h = y @ W_in + b_in (MFMA) ----------------
__global__ __launch_bounds__(256) void k_in_mfma(const float* __restrict__ y,
                                                 const char* __restrict__ imgWin,
                                                 const float* __restrict__ bi,
                                                 float* __restrict__ h) {
    int tid = threadIdx.x, w = tid >> 6, lane = tid & 63;
    int l15 = lane & 15, kg = lane >> 4;
    int m0 = blockIdx.x * 64 + w * 16;
    const float* yr = y + (size_t)(m0 + l15) * CODE;
    f32x4 acc[8];
#pragma unroll
    for (int nt = 0; nt < 8; nt++) { f32x4 z = {0.f,0.f,0.f,0.f}; acc[nt] = z; }
#pragma unroll 4
    for (int ks = 0; ks < 32; ks++) {
        short8 a = cvtfrag(yr + ks * 32 + kg * 8);
        const char* bp = imgWin + ks * 64 + kg * 16;
#pragma unroll
        for (int nt = 0; nt < 8; nt++) {
            short8 b = *(const short8*)(bp + (nt * 16 + l15) * 2048);
            acc[nt] = __builtin_amdgcn_mfma_f32_16x16x32_bf16(a, b, acc[nt], 0, 0, 0);
        }
    }
#pragma unroll
    for (int nt = 0; nt < 8; nt++) {
        int cc = nt * 16 + l15;
        float bb = bi[cc];
#pragma unroll
        for (int r = 0; r < 4; r++)
            h[(size_t)(m0 + kg * 4 + r) * H + cc] = acc[nt][r] + bb;
    }
}

// ---------------- LayerNorm ----------------
__global__ void k_ln(const float* __restrict__ h, const float* __restrict__ g,
                     const float* __restrict__ b, float* __restrict__ hn) {
    int wave = threadIdx.x >> 6, lane = threadIdx.x & 63;
    int n = blockIdx.x * 4 + wave;
    const float* hr = h + (size_t)n * H;
    float x0 = hr[lane], x1 = hr[lane + 64];
    float s = x0 + x1;
#pragma unroll
    for (int off = 32; off; off >>= 1) s += __shfl_xor(s, off);
    float mu = s * (1.0f / 128.0f);
    float d0 = x0 - mu, d1 = x1 - mu;
    float v = d0 * d0 + d1 * d1;
#pragma unroll
    for (int off = 32; off; off >>= 1) v += __shfl_xor(v, off);
    float rs = rsqrtf(v * (1.0f / 128.0f) + 1e-5f);
    float* o = hn + (size_t)n * H;
    o[lane]      = d0 * rs * g[lane]      + b[lane];
    o[lane + 64] = d1 * rs * g[lane + 64] + b[lane + 64];
}

// ---------------- P = hn @ [W1a|W1b] (+b1 on upper half), OUTPUT BF16 ----------------
__global__ __launch_bounds__(256) void k_P_mfma(const float* __restrict__ hn,
                                                const char* __restrict__ imgP,
                                                const float* __restrict__ b1,
                                                unsigned short* __restrict__ Pb) {
    int bid = blockIdx.x;
    int rowblk = bid >> 1, nc = bid & 1;
    int tid = threadIdx.x, w = tid >> 6, lane = tid & 63;
    int l15 = lane & 15, kg = lane >> 4;
    int m0 = rowblk * 64 + w * 16;
    const float* hr = hn + (size_t)(m0 + l15) * H;
    short8 a[4];
#pragma unroll
    for (int ks = 0; ks < 4; ks++) a[ks] = cvtfrag(hr + ks * 32 + kg * 8);
    f32x4 acc[8];
#pragma unroll
    for (int nt = 0; nt < 8; nt++) { f32x4 z = {0.f,0.f,0.f,0.f}; acc[nt] = z; }
#pragma unroll
    for (int ks = 0; ks < 4; ks++) {
        const char* bp = imgP + (size_t)(nc * 128) * 256 + ks * 64 + kg * 16;
#pragma unroll
        for (int nt = 0; nt < 8; nt++) {
            short8 b = *(const short8*)(bp + (nt * 16 + l15) * 256);
            acc[nt] = __builtin_amdgcn_mfma_f32_16x16x32_bf16(a[ks], b, acc[nt], 0, 0, 0);
        }
    }
#pragma unroll
    for (int nt = 0; nt < 8; nt++) {
        int jj = nc * 128 + nt * 16 + l15;
        float add = nc ? b1[nt * 16 + l15] : 0.0f;
#pragma unroll
        for (int r = 0; r < 4; r++)
            Pb[(size_t)(m0 + kg * 4 + r) * 256 + jj] = f2bf(acc[nt][r] + add);
    }
}

// ---------------- fused edge phase: LDS-staged stencil, 8 waves/plane ----------------
// Block = 512 thr = 8 waves: 4 M-tiles x 2 offset-groups (13 offsets each).
// LDS: 3 P1 x-planes (swizzled) + eW2^T B-tile (swizzled; aliased as f32 reduce
// buffer after the compute phase). B reads are ds_reads, not L2 round-trips.
__global__ __launch_bounds__(512) void k_edge_sten(
        const unsigned short* __restrict__ Pb, const char* __restrict__ imgW2,
        const float* __restrict__ w256f, const float* __restrict__ b2,
        char* __restrict__ aggb) {
    __shared__ __align__(16) char sP1[3 * 16384];       // 48 KB
    __shared__ __align__(16) char sB[64 * RSTR * 4];    // 33.3 KB: B, then red f32
    float* red = (float*)sB;

    int tid = threadIdx.x, wv = tid >> 6, lane = tid & 63;
    int mt = wv & 3, grp = wv >> 2;
    int l15 = lane & 15, kg = lane >> 4;
    int n0 = blockIdx.x * 64;
    int x = (n0 >> 6) & 7;

    // stage 3 x-planes of P1 (swizzled: unit ^ (row&15))
#pragma unroll
    for (int i = 0; i < 6; i++) {
        int u = tid + i * 512;
        int p = u >> 10, rem = u & 1023;
        int row = rem >> 4, unit = rem & 15;
        int xp = x + p - 1;
        if ((unsigned)xp < 8u) {
            const char* src = (const char*)Pb + (size_t)(n0 + (p - 1) * 64 + row) * 512 + unit * 16;
            *(uint4*)(sP1 + p * 16384 + row * 256 + ((unit ^ (row & 15)) << 4)) = *(const uint4*)src;
        }
    }
    // stage B = eW2^T [128][128] bf16 (swizzled the same way)
#pragma unroll
    for (int i = 0; i < 4; i++) {
        int u = tid + i * 512;
        int row = u >> 4, unit = u & 15;
        *(uint4*)(sB + row * 256 + ((unit ^ (row & 15)) << 4)) =
            *(const uint4*)(imgW2 + row * 256 + unit * 16);
    }
    __syncthreads();

    int rowbase = mt * 16 + l15;                   // A-row in plane (0..63)
    int ya = rowbase >> 3, za = rowbase & 7;

    // own-node P2 slice and w256 slice (k = ks*32 + kg*8 + i)
    float p2f[32], wf[32];
    const char* p2p = (const char*)Pb + (size_t)(n0 + rowbase) * 512 + 256;
#pragma unroll
    for (int ks = 0; ks < 4; ks++) {
        short8 s = *(const short8*)(p2p + ks * 64 + kg * 16);
#pragma unroll
        for (int i = 0; i < 8; i++) p2f[ks * 8 + i] = bf2f(s[i]);
        float4 a4 = *(const float4*)(w256f + ks * 32 + kg * 8);
        float4 b4 = *(const float4*)(w256f + ks * 32 + kg * 8 + 4);
        wf[ks*8+0]=a4.x; wf[ks*8+1]=a4.y; wf[ks*8+2]=a4.z; wf[ks*8+3]=a4.w;
        wf[ks*8+4]=b4.x; wf[ks*8+5]=b4.y; wf[ks*8+6]=b4.z; wf[ks*8+7]=b4.w;
    }
    float b2v[8];
#pragma unroll
    for (int nt = 0; nt < 8; nt++) b2v[nt] = b2[nt * 16 + l15];

    float accag[8][4];
#pragma unroll
    for (int nt = 0; nt < 8; nt++)
#pragma unroll
        for (int r = 0; r < 4; r++) accag[nt][r] = 0.0f;

    int ye = mt * 2 + (kg >> 1), ze = (kg & 1) * 4;  // C-row coords

    for (int o = grp * 13; o < grp * 13 + 13; ++o) {
        int dx = SDX[o], dy = SDY[o], dz = SDZ[o];
        if ((unsigned)(x + dx) >= 8u) continue;      // uniform skip
        float d = sqrtf((float)(4 * (dx * dx + dy * dy + dz * dz)));
        bool va = ((unsigned)(ya + dy) < 8u) & ((unsigned)(za + dz) < 8u);
        int rowr = va ? (rowbase + dy * 8 + dz) : rowbase;
        const char* ap = sP1 + (dx + 1) * 16384 + rowr * 256;
        int rsw = rowr & 15;

        f32x4 c[8];
#pragma unroll
        for (int nt = 0; nt < 8; nt++) { f32x4 z4 = {0.f,0.f,0.f,0.f}; c[nt] = z4; }
#pragma unroll
        for (int ks = 0; ks < 4; ks++) {
            short8 s = *(const short8*)(ap + (((ks * 4 + kg) ^ rsw) << 4));
            short8 a;
#pragma unroll
            for (int i = 0; i < 8; i++) {
                float v = bf2f(s[i]) + p2f[ks * 8 + i] + d * wf[ks * 8 + i];
                a[i] = (short)f2bf(silu(v));
            }
#pragma unroll
            for (int nt = 0; nt < 8; nt++) {
                int brow = nt * 16 + l15;
                short8 b = *(const short8*)(sB + brow * 256 + (((ks * 4 + kg) ^ l15) << 4));
                c[nt] = __builtin_amdgcn_mfma_f32_16x16x32_bf16(a, b, c[nt], 0, 0, 0);
            }
        }
#pragma unroll
        for (int r = 0; r < 4; r++) {
            bool vr = ((unsigned)(ye + dy) < 8u) & ((unsigned)(ze + r + dz) < 8u);
#pragma unroll
            for (int nt = 0; nt < 8; nt++) {
                float v = silu(c[nt][r] + b2v[nt]);
                accag[nt][r] += vr ? v : 0.0f;
            }
        }
    }

    // barrier-sequenced cross-group reduce (deterministic); red aliases sB
    __syncthreads();                                 // all B reads done
    if (grp == 0) {
#pragma unroll
        for (int nt = 0; nt < 8; nt++)
#pragma unroll
            for (int r = 0; r < 4; r++)
                red[(mt * 16 + kg * 4 + r) * RSTR + nt * 16 + l15] = accag[nt][r];
    }
    __syncthreads();
    if (grp == 1) {
#pragma unroll
        for (int nt = 0; nt < 8; nt++)
#pragma unroll
            for (int r = 0; r < 4; r++)
                red[(mt * 16 + kg * 4 + r) * RSTR + nt * 16 + l15] += accag[nt][r];
    }
    __syncthreads();

    for (int i = tid; i < 8192; i += 512) {
        int row = i >> 7, col = i & 127;
        int node = n0 + row;
        int yy = row >> 3, zz = row & 7;
        int degc = (1 + (x > 0) + (x < 7)) * (1 + (yy > 0) + (yy < 7))
                 * (1 + (zz > 0) + (zz < 7)) - 1;
        *(unsigned short*)(aggb + (size_t)node * 256 + col * 2) =
            f2bf(red[row * RSTR + col] * (1.0f / (float)degc));
    }
}

// ---------------- fused node MLP + residual (MFMA x2) ----------------
__global__ __launch_bounds__(256) void k_node_mfma(
        const float* __restrict__ hn, const char* __restrict__ aggb,
        const char* __restrict__ imgN1, const float* __restrict__ nb1,
        const char* __restrict__ imgN2, const float* __restrict__ nb2,
        float* __restrict__ h) {
    __shared__ __align__(16) char sM[4][16 * 272];
    int tid = threadIdx.x, w = tid >> 6, lane = tid & 63;
    int l15 = lane & 15, kg = lane >> 4;
    int m0 = blockIdx.x * 64 + w * 16;
    const float* hr = hn + (size_t)(m0 + l15) * H;
    const char*  ar = aggb + (size_t)(m0 + l15) * 256;

    f32x4 acc[8];
#pragma unroll
    for (int nt = 0; nt < 8; nt++) { f32x4 z = {0.f,0.f,0.f,0.f}; acc[nt] = z; }
#pragma unroll
    for (int ks = 0; ks < 8; ks++) {
        short8 a;
        if (ks < 4) a = cvtfrag(hr + ks * 32 + kg * 8);
        else        a = *(const short8*)(ar + (ks - 4) * 64 + kg * 16);
        const char* bp = imgN1 + ks * 64 + kg * 16;
#pragma unroll
        for (int nt = 0; nt < 8; nt++) {
            short8 b = *(const short8*)(bp + (nt * 16 + l15) * 512);
            acc[nt] = __builtin_amdgcn_mfma_f32_16x16x32_bf16(a, b, acc[nt], 0, 0, 0);
        }
    }
#pragma unroll
    for (int nt = 0; nt < 8; nt++) {
        int cc = nt * 16 + l15;
        float bb = nb1[cc];
#pragma unroll
        for (int r = 0; r < 4; r++) {
            float v = silu(acc[nt][r] + bb);
            *(unsigned short*)(&sM[w][(kg * 4 + r) * 272 + cc * 2]) = f2bf(v);
        }
    }
    f32x4 acc2[8];
#pragma unroll
    for (int nt = 0; nt < 8; nt++) { f32x4 z = {0.f,0.f,0.f,0.f}; acc2[nt] = z; }
#pragma unroll
    for (int ks = 0; ks < 4; ks++) {
        short8 a = *(const short8*)(&sM[w][l15 * 272 + ks * 64 + kg * 16]);
        const char* bp = imgN2 + ks * 64 + kg * 16;
#pragma unroll
        for (int nt = 0; nt < 8; nt++) {
            short8 b = *(const short8*)(bp + (nt * 16 + l15) * 256);
            acc2[nt] = __builtin_amdgcn_mfma_f32_16x16x32_bf16(a, b, acc2[nt], 0, 0, 0);
        }
    }
#pragma unroll
    for (int nt = 0; nt < 8; nt++) {
        int cc = nt * 16 + l15;
        float bb = nb2[cc];
#pragma unroll
        for (int r = 0; r < 4; r++) {
            size_t idx = (size_t)(m0 + kg * 4 + r) * H + cc;
            h[idx] = hn[idx] + acc2[nt][r] + bb;
        }
    }
}

// ---------------- out = h @ W_out + b_out (MFMA, N-parallel) ----------------
__global__ __launch_bounds__(256) void k_out_mfma(const float* __restrict__ h,
                                                  const char* __restrict__ imgWout,
                                                  const float* __restrict__ bo,
                                                  float* __restrict__ out) {
    int bid = blockIdx.x;
    int rowblk = bid >> 3, nc = bid & 7;
    int tid = threadIdx.x, w = tid >> 6, lane = tid & 63;
    int l15 = lane & 15, kg = lane >> 4;
    int m0 = rowblk * 64 + w * 16;
    const float* hr = h + (size_t)(m0 + l15) * H;
    short8 a[4];
#pragma unroll
    for (int ks = 0; ks < 4; ks++) a[ks] = cvtfrag(hr + ks * 32 + kg * 8);
    f32x4 acc[8];
#pragma unroll
    for (int nt = 0; nt < 8; nt++) { f32x4 z = {0.f,0.f,0.f,0.f}; acc[nt] = z; }
#pragma unroll
    for (int ks = 0; ks < 4; ks++) {
        const char* bp = imgWout + (size_t)(nc * 128) * 256 + ks * 64 + kg * 16;
#pragma unroll
        for (int nt = 0; nt < 8; nt++) {
            short8 b = *(const short8*)(bp + (nt * 16 + l15) * 256);
            acc[nt] = __builtin_amdgcn_mfma_f32_16x16x32_bf16(a[ks], b, acc[nt], 0, 0, 0);
        }
    }
#pragma unroll
    for (int nt = 0; nt < 8; nt++) {
        int cc = nc * 128 + nt * 16 + l15;
        float bb = bo[cc];
#pragma unroll
        for (int r = 0; r < 4; r++)
            out[(size_t)(m0 + kg * 4 + r) * 1024 + cc] = acc[nt][r] + bb;
    }
}

extern "C" void kernel_launch(void* const* d_in, const int* in_sizes, int n_in,
                              void* d_out, int out_size, void* d_ws, size_t ws_size,
                              hipStream_t stream) {
    const float* y     = (const float*)d_in[0];
    const float* W_in  = (const float*)d_in[3];
    const float* b_in  = (const float*)d_in[4];
    const float* ln_g  = (const float*)d_in[5];
    const float* ln_b  = (const float*)d_in[6];
    const float* eW1   = (const float*)d_in[7];
    const float* eb1   = (const float*)d_in[8];
    const float* eW2   = (const float*)d_in[9];
    const float* eb2   = (const float*)d_in[10];
    const float* nW1   = (const float*)d_in[11];
    const float* nb1   = (const float*)d_in[12];
    const float* nW2   = (const float*)d_in[13];
    const float* nb2   = (const float*)d_in[14];
    const float* W_out = (const float*)d_in[15];
    const float* b_out = (const float*)d_in[16];

    char* wsb = (char*)d_ws;
    float* h    = (float*)(wsb + OFF_H);
    float* hn   = (float*)(wsb + OFF_HN);
    unsigned short* Pb = (unsigned short*)(wsb + OFF_PBUF);
    char*  aggb = wsb + OFF_AGGB;

    k_prep<<<655360 / 256, 256, 0, stream>>>(W_in, W_out, eW1, nW1, nW2, eW2, wsb);
    k_in_mfma<<<NN / 64, 256, 0, stream>>>(y, wsb + OFF_WIN, b_in, h);
    for (int l = 0; l < 4; ++l) {
        k_ln<<<NN / 4, 256, 0, stream>>>(h, ln_g + l * H, ln_b + l * H, hn);
        k_P_mfma<<<NN / 64 * 2, 256, 0, stream>>>(hn, wsb + OFF_P + (size_t)l * 65536,
                                                  eb1 + l * H, Pb);
        k_edge_sten<<<NN / 64, 512, 0, stream>>>(Pb, wsb + OFF_W2 + (size_t)l * 32768,
                                                 eW1 + (size_t)l * 257 * H + 256 * H,
                                                 eb2 + l * H, aggb);
        k_node_mfma<<<NN / 64, 256, 0, stream>>>(hn, aggb,
                                                 wsb + OFF_N1 + (size_t)l * 65536, nb1 + l * H,
                                                 wsb + OFF_N2 + (size_t)l * 32768, nb2 + l * H, h);
    }
    k_out_mfma<<<NN / 64 * 8, 256, 0, stream>>>(h, wsb + OFF_WOUT, b_out, (float*)d_out);
}

// Round 10
// 600.075 us; speedup vs baseline: 1.5294x; 1.0230x over previous
//
#include <hip/hip_runtime.h>
#include <math.h>

#define NN 16384
#define H 128
#define CODE 1024
#define RSTR 128   // red stride f32 words; LDS budget: 48K(P1)+32K(B/red)=80K -> 2 blocks/CU

typedef __attribute__((ext_vector_type(8))) short short8;
typedef __attribute__((ext_vector_type(4))) float f32x4;

// ---- ws layout (bytes) ----
#define OFF_WIN   0u            // [128][1024] bf16, stride 2048
#define OFF_WOUT  262144u       // [1024][128] bf16, stride 256
#define OFF_P     524288u       // 4 x [256][128] bf16 (eW1 split), stride 256
#define OFF_N1    786432u       // 4 x [128][256] bf16, stride 512
#define OFF_N2    1048576u      // 4 x [128][128] bf16, stride 256
#define OFF_W2    1179648u      // 4 x [128][128] bf16 eW2^T, stride 256
#define OFF_H     1318912u                   // h   fp32  8388608
#define OFF_HN    (OFF_H + 8388608u)         // hn  fp32  8388608
#define OFF_PBUF  (OFF_HN + 8388608u)        // P  BF16 [NN][256]  8388608
#define OFF_AGGB  (OFF_PBUF + 16777216u)     // agg bf16  4194304

__device__ __forceinline__ float silu(float x) { return x / (1.0f + __expf(-x)); }

__device__ __forceinline__ unsigned short f2bf(float f) {
    unsigned int u = __float_as_uint(f);
    u = (u + 0x7FFFu + ((u >> 16) & 1u)) >> 16;
    return (unsigned short)u;
}

__device__ __forceinline__ float bf2f(short s) {
    return __uint_as_float(((unsigned)(unsigned short)s) << 16);
}

// pack 8 f32 -> 8 bf16 via v_cvt_pk_bf16_f32 (RNE); dst.lo = src0, dst.hi = src1
__device__ __forceinline__ short8 pack_bf16_8(const float* v) {
    union { unsigned u[4]; short8 s; } r;
    asm("v_cvt_pk_bf16_f32 %0, %1, %2" : "=v"(r.u[0]) : "v"(v[0]), "v"(v[1]));
    asm("v_cvt_pk_bf16_f32 %0, %1, %2" : "=v"(r.u[1]) : "v"(v[2]), "v"(v[3]));
    asm("v_cvt_pk_bf16_f32 %0, %1, %2" : "=v"(r.u[2]) : "v"(v[4]), "v"(v[5]));
    asm("v_cvt_pk_bf16_f32 %0, %1, %2" : "=v"(r.u[3]) : "v"(v[6]), "v"(v[7]));
    return r.s;
}

__device__ __forceinline__ short8 cvtfrag(const float* p) {
    float v[8];
    float4 a = *(const float4*)p;
    float4 b = *(const float4*)(p + 4);
    v[0]=a.x; v[1]=a.y; v[2]=a.z; v[3]=a.w; v[4]=b.x; v[5]=b.y; v[6]=b.z; v[7]=b.w;
    return pack_bf16_8(v);
}

// 26-stencil offsets, grouped 13/13 across wave-groups
__device__ const int SDX[26] = {-1,-1,-1,-1, 1, 1, 1, 1,  -1,-1,-1,-1, 0,  0, 0, 0, 1, 1, 1, 1,  -1, 1, 0, 0, 0, 0};
__device__ const int SDY[26] = {-1,-1, 1, 1,-1,-1, 1, 1,  -1, 0, 0, 1,-1, -1, 1, 1,-1, 0, 0, 1,   0, 0,-1, 1, 0, 0};
__device__ const int SDZ[26] = {-1, 1,-1, 1,-1, 1,-1, 1,   0,-1, 1, 0,-1,  1,-1, 1, 0,-1, 1, 0,   0, 0, 0, 0,-1, 1};

// transposed bf16 weight images for all GEMMs
__global__ void k_prep(const float* __restrict__ W_in, const float* __restrict__ W_out,
                       const float* __restrict__ eW1, const float* __restrict__ nW1,
                       const float* __restrict__ nW2, const float* __restrict__ eW2,
                       char* __restrict__ base) {
    int t = blockIdx.x * 256 + threadIdx.x;
    if (t < 131072) {
        int n = t >> 10, k = t & 1023;
        *(unsigned short*)(base + OFF_WIN + n * 2048 + k * 2) = f2bf(W_in[k * 128 + n]);
        return;
    }
    t -= 131072;
    if (t < 131072) {
        int n = t >> 7, k = t & 127;
        *(unsigned short*)(base + OFF_WOUT + n * 256 + k * 2) = f2bf(W_out[k * 1024 + n]);
        return;
    }
    t -= 131072;
    if (t < 131072) {
        int l = t >> 15, r = t & 32767;
        int jj = r >> 7, k = r & 127;
        const float* W = eW1 + (size_t)l * 257 * 128;
        float v = (jj < 128) ? W[k * 128 + jj] : W[(128 + k) * 128 + (jj - 128)];
        *(unsigned short*)(base + OFF_P + (size_t)l * 65536 + jj * 256 + k * 2) = f2bf(v);
        return;
    }
    t -= 131072;
    if (t < 131072) {
        int l = t >> 15, r = t & 32767;
        int n = r >> 8, k = r & 255;
        *(unsigned short*)(base + OFF_N1 + (size_t)l * 65536 + n * 512 + k * 2) =
            f2bf(nW1[(size_t)l * 256 * 128 + k * 128 + n]);
        return;
    }
    t -= 131072;
    if (t < 65536) {
        int l = t >> 14, r = t & 16383;
        int n = r >> 7, k = r & 127;
        *(unsigned short*)(base + OFF_N2 + (size_t)l * 32768 + n * 256 + k * 2) =
            f2bf(nW2[(size_t)l * 128 * 128 + k * 128 + n]);
        return;
    }
    t -= 65536;
    if (t < 65536) {
        int l = t >> 14, r = t & 16383;
        int n = r >> 7, k = r & 127;
        *(unsigned short*)(base + OFF_W2 + (size_t)l * 32768 + n * 256 + k * 2) =
            f2bf(eW2[(size_t)l * 128 * 128 + k * 128 + n]);
    }
}

// ---------------- h = y @ W_in + b_in (MFMA) ----------------
__global__ __launch_bounds__(256) void k_in_mfma(const float* __restrict__ y,
                                                 const char* __restrict__ imgWin,
                                                 const float* __restrict__ bi,
                                                 float* __restrict__ h) {
    int tid = threadIdx.x, w = tid >> 6, lane = tid & 63;
    int l15 = lane & 15, kg = lane >> 4;
    int m0 = blockIdx.x * 64 + w * 16;
    const float* yr = y + (size_t)(m0 + l15) * CODE;
    f32x4 acc[8];
#pragma unroll
    for (int nt = 0; nt < 8; nt++) { f32x4 z = {0.f,0.f,0.f,0.f}; acc[nt] = z; }
#pragma unroll 4
    for (int ks = 0; ks < 32; ks++) {
        short8 a = cvtfrag(yr + ks * 32 + kg * 8);
        const char* bp = imgWin + ks * 64 + kg * 16;
#pragma unroll
        for (int nt = 0; nt < 8; nt++) {
            short8 b = *(const short8*)(bp + (nt * 16 + l15) * 2048);
            acc[nt] = __builtin_amdgcn_mfma_f32_16x16x32_bf16(a, b, acc[nt], 0, 0, 0);
        }
    }
#pragma unroll
    for (int nt = 0; nt < 8; nt++) {
        int cc = nt * 16 + l15;
        float bb = bi[cc];
#pragma unroll
        for (int r = 0; r < 4; r++)
            h[(size_t)(m0 + kg * 4 + r) * H + cc] = acc[nt][r] + bb;
    }
}

// ---------------- fused LN + P GEMM: hn = LN(h); P = hn@[W1a|W1b] (+b1 hi) ----------------
// Each row is held by the 4 lanes {l15+16*kg}; LN stats via shfl_xor(16/32).
// nc==0 blocks also write hn (f32) for k_node's residual/A reads.
__global__ __launch_bounds__(256) void k_lnP(const float* __restrict__ h,
                                             const float* __restrict__ g,
                                             const float* __restrict__ bln,
                                             const char* __restrict__ imgP,
                                             const float* __restrict__ b1,
                                             float* __restrict__ hn,
                                             unsigned short* __restrict__ Pb) {
    int bid = blockIdx.x;
    int rowblk = bid >> 1, nc = bid & 1;
    int tid = threadIdx.x, w = tid >> 6, lane = tid & 63;
    int l15 = lane & 15, kg = lane >> 4;
    int m0 = rowblk * 64 + w * 16;
    int row = m0 + l15;
    const float* hr = h + (size_t)row * H;

    float hv[32];
#pragma unroll
    for (int ks = 0; ks < 4; ks++) {
        float4 a4 = *(const float4*)(hr + ks * 32 + kg * 8);
        float4 b4 = *(const float4*)(hr + ks * 32 + kg * 8 + 4);
        hv[ks*8+0]=a4.x; hv[ks*8+1]=a4.y; hv[ks*8+2]=a4.z; hv[ks*8+3]=a4.w;
        hv[ks*8+4]=b4.x; hv[ks*8+5]=b4.y; hv[ks*8+6]=b4.z; hv[ks*8+7]=b4.w;
    }
    float s = 0.0f;
#pragma unroll
    for (int i = 0; i < 32; i++) s += hv[i];
    s += __shfl_xor(s, 16); s += __shfl_xor(s, 32);
    float mu = s * (1.0f / 128.0f);
    float vs = 0.0f;
#pragma unroll
    for (int i = 0; i < 32; i++) { float d = hv[i] - mu; vs += d * d; }
    vs += __shfl_xor(vs, 16); vs += __shfl_xor(vs, 32);
    float rs = rsqrtf(vs * (1.0f / 128.0f) + 1e-5f);

#pragma unroll
    for (int ks = 0; ks < 4; ks++) {
        float4 g0 = *(const float4*)(g + ks * 32 + kg * 8);
        float4 g1 = *(const float4*)(g + ks * 32 + kg * 8 + 4);
        float4 c0 = *(const float4*)(bln + ks * 32 + kg * 8);
        float4 c1 = *(const float4*)(bln + ks * 32 + kg * 8 + 4);
        hv[ks*8+0] = (hv[ks*8+0]-mu)*rs*g0.x + c0.x;
        hv[ks*8+1] = (hv[ks*8+1]-mu)*rs*g0.y + c0.y;
        hv[ks*8+2] = (hv[ks*8+2]-mu)*rs*g0.z + c0.z;
        hv[ks*8+3] = (hv[ks*8+3]-mu)*rs*g0.w + c0.w;
        hv[ks*8+4] = (hv[ks*8+4]-mu)*rs*g1.x + c1.x;
        hv[ks*8+5] = (hv[ks*8+5]-mu)*rs*g1.y + c1.y;
        hv[ks*8+6] = (hv[ks*8+6]-mu)*rs*g1.z + c1.z;
        hv[ks*8+7] = (hv[ks*8+7]-mu)*rs*g1.w + c1.w;
    }
    if (nc == 0) {
        float* o = hn + (size_t)row * H;
#pragma unroll
        for (int ks = 0; ks < 4; ks++) {
            *(float4*)(o + ks * 32 + kg * 8)     = *(float4*)&hv[ks*8];
            *(float4*)(o + ks * 32 + kg * 8 + 4) = *(float4*)&hv[ks*8+4];
        }
    }
    short8 a[4];
#pragma unroll
    for (int ks = 0; ks < 4; ks++) a[ks] = pack_bf16_8(&hv[ks*8]);

    f32x4 acc[8];
#pragma unroll
    for (int nt = 0; nt < 8; nt++) { f32x4 z = {0.f,0.f,0.f,0.f}; acc[nt] = z; }
#pragma unroll
    for (int ks = 0; ks < 4; ks++) {
        const char* bp = imgP + (size_t)(nc * 128) * 256 + ks * 64 + kg * 16;
#pragma unroll
        for (int nt = 0; nt < 8; nt++) {
            short8 b = *(const short8*)(bp + (nt * 16 + l15) * 256);
            acc[nt] = __builtin_amdgcn_mfma_f32_16x16x32_bf16(a[ks], b, acc[nt], 0, 0, 0);
        }
    }
#pragma unroll
    for (int nt = 0; nt < 8; nt++) {
        int jj = nc * 128 + nt * 16 + l15;
        float add = nc ? b1[nt * 16 + l15] : 0.0f;
#pragma unroll
        for (int r = 0; r < 4; r++)
            Pb[(size_t)(m0 + kg * 4 + r) * 256 + jj] = f2bf(acc[nt][r] + add);
    }
}

// ---------------- fused edge phase: LDS-staged stencil, 8 waves/plane ----------------
__global__ __launch_bounds__(512) void k_edge_sten(
        const unsigned short* __restrict__ Pb, const char* __restrict__ imgW2,
        const float* __restrict__ w256f, const float* __restrict__ b2,
        char* __restrict__ aggb) {
    __shared__ __align__(16) char sP1[3 * 16384];       // 48 KB
    __shared__ __align__(16) char sB[64 * RSTR * 4];    // 32 KB: B, then red f32
    float* red = (float*)sB;

    int tid = threadIdx.x, wv = tid >> 6, lane = tid & 63;
    int mt = wv & 3, grp = wv >> 2;
    int l15 = lane & 15, kg = lane >> 4;
    int n0 = blockIdx.x * 64;
    int x = (n0 >> 6) & 7;

    // stage 3 x-planes of P1 (swizzled: unit ^ (row&15))
#pragma unroll
    for (int i = 0; i < 6; i++) {
        int u = tid + i * 512;
        int p = u >> 10, rem = u & 1023;
        int row = rem >> 4, unit = rem & 15;
        int xp = x + p - 1;
        if ((unsigned)xp < 8u) {
            const char* src = (const char*)Pb + (size_t)(n0 + (p - 1) * 64 + row) * 512 + unit * 16;
            *(uint4*)(sP1 + p * 16384 + row * 256 + ((unit ^ (row & 15)) << 4)) = *(const uint4*)src;
        }
    }
    // stage B = eW2^T [128][128] bf16 (swizzled)
#pragma unroll
    for (int i = 0; i < 4; i++) {
        int u = tid + i * 512;
        int row = u >> 4, unit = u & 15;
        *(uint4*)(sB + row * 256 + ((unit ^ (row & 15)) << 4)) =
            *(const uint4*)(imgW2 + row * 256 + unit * 16);
    }
    __syncthreads();

    int rowbase = mt * 16 + l15;
    int ya = rowbase >> 3, za = rowbase & 7;

    float p2f[32], wf[32];
    const char* p2p = (const char*)Pb + (size_t)(n0 + rowbase) * 512 + 256;
#pragma unroll
    for (int ks = 0; ks < 4; ks++) {
        short8 s = *(const short8*)(p2p + ks * 64 + kg * 16);
#pragma unroll
        for (int i = 0; i < 8; i++) p2f[ks * 8 + i] = bf2f(s[i]);
        float4 a4 = *(const float4*)(w256f + ks * 32 + kg * 8);
        float4 b4 = *(const float4*)(w256f + ks * 32 + kg * 8 + 4);
        wf[ks*8+0]=a4.x; wf[ks*8+1]=a4.y; wf[ks*8+2]=a4.z; wf[ks*8+3]=a4.w;
        wf[ks*8+4]=b4.x; wf[ks*8+5]=b4.y; wf[ks*8+6]=b4.z; wf[ks*8+7]=b4.w;
    }
    float b2v[8];
#pragma unroll
    for (int nt = 0; nt < 8; nt++) b2v[nt] = b2[nt * 16 + l15];

    float accag[8][4];
#pragma unroll
    for (int nt = 0; nt < 8; nt++)
#pragma unroll
        for (int r = 0; r < 4; r++) accag[nt][r] = 0.0f;

    int ye = mt * 2 + (kg >> 1), ze = (kg & 1) * 4;

    for (int o = grp * 13; o < grp * 13 + 13; ++o) {
        int dx = SDX[o], dy = SDY[o], dz = SDZ[o];
        if ((unsigned)(x + dx) >= 8u) continue;
        float d = sqrtf((float)(4 * (dx * dx + dy * dy + dz * dz)));
        bool va = ((unsigned)(ya + dy) < 8u) & ((unsigned)(za + dz) < 8u);
        int rowr = va ? (rowbase + dy * 8 + dz) : rowbase;
        const char* ap = sP1 + (dx + 1) * 16384 + rowr * 256;
        int rsw = rowr & 15;

        f32x4 c[8];
#pragma unroll
        for (int nt = 0; nt < 8; nt++) { f32x4 z4 = {0.f,0.f,0.f,0.f}; c[nt] = z4; }
#pragma unroll
        for (int ks = 0; ks < 4; ks++) {
            short8 s = *(const short8*)(ap + (((ks * 4 + kg) ^ rsw) << 4));
            float vv[8];
#pragma unroll
            for (int i = 0; i < 8; i++) {
                float v = bf2f(s[i]) + p2f[ks * 8 + i] + d * wf[ks * 8 + i];
                vv[i] = silu(v);
            }
            short8 a = pack_bf16_8(vv);
#pragma unroll
            for (int nt = 0; nt < 8; nt++) {
                int brow = nt * 16 + l15;
                short8 b = *(const short8*)(sB + brow * 256 + (((ks * 4 + kg) ^ l15) << 4));
                c[nt] = __builtin_amdgcn_mfma_f32_16x16x32_bf16(a, b, c[nt], 0, 0, 0);
            }
        }
#pragma unroll
        for (int r = 0; r < 4; r++) {
            bool vr = ((unsigned)(ye + dy) < 8u) & ((unsigned)(ze + r + dz) < 8u);
#pragma unroll
            for (int nt = 0; nt < 8; nt++) {
                float v = silu(c[nt][r] + b2v[nt]);
                accag[nt][r] += vr ? v : 0.0f;
            }
        }
    }

    // barrier-sequenced cross-group reduce (deterministic); red aliases sB
    __syncthreads();
    if (grp == 0) {
#pragma unroll
        for (int nt = 0; nt < 8; nt++)
#pragma unroll
            for (int r = 0; r < 4; r++)
                red[(mt * 16 + kg * 4 + r) * RSTR + nt * 16 + l15] = accag[nt][r];
    }
    __syncthreads();
    if (grp == 1) {
#pragma unroll
        for (int nt = 0; nt < 8; nt++)
#pragma unroll
            for (int r = 0; r < 4; r++)
                red[(mt * 16 + kg * 4 + r) * RSTR + nt * 16 + l15] += accag[nt][r];
    }
    __syncthreads();

    for (int i = tid; i < 8192; i += 512) {
        int row = i >> 7, col = i & 127;
        int node = n0 + row;
        int yy = row >> 3, zz = row & 7;
        int degc = (1 + (x > 0) + (x < 7)) * (1 + (yy > 0) + (yy < 7))
                 * (1 + (zz > 0) + (zz < 7)) - 1;
        *(unsigned short*)(aggb + (size_t)node * 256 + col * 2) =
            f2bf(red[row * RSTR + col] * (1.0f / (float)degc));
    }
}

// ---------------- fused node MLP + residual (MFMA x2) ----------------
__global__ __launch_bounds__(256) void k_node_mfma(
        const float* __restrict__ hn, const char* __restrict__ aggb,
        const char* __restrict__ imgN1, const float* __restrict__ nb1,
        const char* __restrict__ imgN2, const float* __restrict__ nb2,
        float* __restrict__ h) {
    __shared__ __align__(16) char sM[4][16 * 272];
    int tid = threadIdx.x, w = tid >> 6, lane = tid & 63;
    int l15 = lane & 15, kg = lane >> 4;
    int m0 = blockIdx.x * 64 + w * 16;
    const float* hr = hn + (size_t)(m0 + l15) * H;
    const char*  ar = aggb + (size_t)(m0 + l15) * 256;

    f32x4 acc[8];
#pragma unroll
    for (int nt = 0; nt < 8; nt++) { f32x4 z = {0.f,0.f,0.f,0.f}; acc[nt] = z; }
#pragma unroll
    for (int ks = 0; ks < 8; ks++) {
        short8 a;
        if (ks < 4) a = cvtfrag(hr + ks * 32 + kg * 8);
        else        a = *(const short8*)(ar + (ks - 4) * 64 + kg * 16);
        const char* bp = imgN1 + ks * 64 + kg * 16;
#pragma unroll
        for (int nt = 0; nt < 8; nt++) {
            short8 b = *(const short8*)(bp + (nt * 16 + l15) * 512);
            acc[nt] = __builtin_amdgcn_mfma_f32_16x16x32_bf16(a, b, acc[nt], 0, 0, 0);
        }
    }
#pragma unroll
    for (int nt = 0; nt < 8; nt++) {
        int cc = nt * 16 + l15;
        float bb = nb1[cc];
#pragma unroll
        for (int r = 0; r < 4; r++) {
            float v = silu(acc[nt][r] + bb);
            *(unsigned short*)(&sM[w][(kg * 4 + r) * 272 + cc * 2]) = f2bf(v);
        }
    }
    f32x4 acc2[8];
#pragma unroll
    for (int nt = 0; nt < 8; nt++) { f32x4 z = {0.f,0.f,0.f,0.f}; acc2[nt] = z; }
#pragma unroll
    for (int ks = 0; ks < 4; ks++) {
        short8 a = *(const short8*)(&sM[w][l15 * 272 + ks * 64 + kg * 16]);
        const char* bp = imgN2 + ks * 64 + kg * 16;
#pragma unroll
        for (int nt = 0; nt < 8; nt++) {
            short8 b = *(const short8*)(bp + (nt * 16 + l15) * 256);
            acc2[nt] = __builtin_amdgcn_mfma_f32_16x16x32_bf16(a, b, acc2[nt], 0, 0, 0);
        }
    }
#pragma unroll
    for (int nt = 0; nt < 8; nt++) {
        int cc = nt * 16 + l15;
        float bb = nb2[cc];
#pragma unroll
        for (int r = 0; r < 4; r++) {
            size_t idx = (size_t)(m0 + kg * 4 + r) * H + cc;
            h[idx] = hn[idx] + acc2[nt][r] + bb;
        }
    }
}

// ---------------- out = h @ W_out + b_out (MFMA, N-parallel) ----------------
__global__ __launch_bounds__(256) void k_out_mfma(const float* __restrict__ h,
                                                  const char* __restrict__ imgWout,
                                                  const float* __restrict__ bo,
                                                  float* __restrict__ out) {
    int bid = blockIdx.x;
    int rowblk = bid >> 3, nc = bid & 7;
    int tid = threadIdx.x, w = tid >> 6, lane = tid & 63;
    int l15 = lane & 15, kg = lane >> 4;
    int m0 = rowblk * 64 + w * 16;
    const float* hr = h + (size_t)(m0 + l15) * H;
    short8 a[4];
#pragma unroll
    for (int ks = 0; ks < 4; ks++) a[ks] = cvtfrag(hr + ks * 32 + kg * 8);
    f32x4 acc[8];
#pragma unroll
    for (int nt = 0; nt < 8; nt++) { f32x4 z = {0.f,0.f,0.f,0.f}; acc[nt] = z; }
#pragma unroll
    for (int ks = 0; ks < 4; ks++) {
        const char* bp = imgWout + (size_t)(nc * 128) * 256 + ks * 64 + kg * 16;
#pragma unroll
        for (int nt = 0; nt < 8; nt++) {
            short8 b = *(const short8*)(bp + (nt * 16 + l15) * 256);
            acc[nt] = __builtin_amdgcn_mfma_f32_16x16x32_bf16(a[ks], b, acc[nt], 0, 0, 0);
        }
    }
#pragma unroll
    for (int nt = 0; nt < 8; nt++) {
        int cc = nc * 128 + nt * 16 + l15;
        float bb = bo[cc];
#pragma unroll
        for (int r = 0; r < 4; r++)
            out[(size_t)(m0 + kg * 4 + r) * 1024 + cc] = acc[nt][r] + bb;
    }
}

extern "C" void kernel_launch(void* const* d_in, const int* in_sizes, int n_in,
                              void* d_out, int out_size, void* d_ws, size_t ws_size,
                              hipStream_t stream) {
    const float* y     = (const float*)d_in[0];
    const float* W_in  = (const float*)d_in[3];
    const float* b_in  = (const float*)d_in[4];
    const float* ln_g  = (const float*)d_in[5];
    const float* ln_b  = (const float*)d_in[6];
    const float* eW1   = (const float*)d_in[7];
    const float* eb1   = (const float*)d_in[8];
    const float* eW2   = (const float*)d_in[9];
    const float* eb2   = (const float*)d_in[10];
    const float* nW1   = (const float*)d_in[11];
    const float* nb1   = (const float*)d_in[12];
    const float* nW2   = (const float*)d_in[13];
    const float* nb2   = (const float*)d_in[14];
    const float* W_out = (const float*)d_in[15];
    const float* b_out = (const float*)d_in[16];

    char* wsb = (char*)d_ws;
    float* h    = (float*)(wsb + OFF_H);
    float* hn   = (float*)(wsb + OFF_HN);
    unsigned short* Pb = (unsigned short*)(wsb + OFF_PBUF);
    char*  aggb = wsb + OFF_AGGB;

    k_prep<<<655360 / 256, 256, 0, stream>>>(W_in, W_out, eW1, nW1, nW2, eW2, wsb);
    k_in_mfma<<<NN / 64, 256, 0, stream>>>(y, wsb + OFF_WIN, b_in, h);
    for (int l = 0; l < 4; ++l) {
        k_lnP<<<NN / 64 * 2, 256, 0, stream>>>(h, ln_g + l * H, ln_b + l * H,
                                               wsb + OFF_P + (size_t)l * 65536,
                                               eb1 + l * H, hn, Pb);
        k_edge_sten<<<NN / 64, 512, 0, stream>>>(Pb, wsb + OFF_W2 + (size_t)l * 32768,
                                                 eW1 + (size_t)l * 257 * H + 256 * H,
                                                 eb2 + l * H, aggb);
        k_node_mfma<<<NN / 64, 256, 0, stream>>>(hn, aggb,
                                                 wsb + OFF_N1 + (size_t)l * 65536, nb1 + l * H,
                                                 wsb + OFF_N2 + (size_t)l * 32768, nb2 + l * H, h);
    }
    k_out_mfma<<<NN / 64 * 8, 256, 0, stream>>>(h, wsb + OFF_WOUT, b_out, (float*)d_out);
}